// Round 1
// 361.411 us; speedup vs baseline: 1.0716x; 1.0716x over previous
//
#include <hip/hip_runtime.h>

// Problem constants (from reference)
#define NN 8192
#define IN_DIM 512
#define NUM_CLASSES 16
#define PER_CLASS 512
#define KK 256
#define NSEL (NUM_CLASSES * KK)   // 4096

// Native clang vector type — accepted by __builtin_nontemporal_* (HIP's
// float4 is a class and is rejected).
typedef float vfloat4 __attribute__((ext_vector_type(4)));

// ---------------------------------------------------------------------------
// Kernel 1 (fused prep): block-specialized.
//   Blocks 0..15: single-pass member scan for class = blockIdx.x.
//     Each thread owns 16 consecutive ids -> popcount -> block prefix scan
//     (1 barrier) -> ordered scatter. Member list is globally ascending
//     (thread ranges are contiguous), matching jnp.nonzero order exactly.
//   Blocks 16..1039: scores[i] = sigmoid((dot(X[i],W)+b)/100), one wave/row,
//     8 rows per block. Runs concurrently with the scan blocks.
// ---------------------------------------------------------------------------
__global__ __launch_bounds__(512) void prep_kernel(
    const float* __restrict__ X, const float* __restrict__ W,
    const float* __restrict__ b, const int* __restrict__ mask,
    float* __restrict__ scores, int* __restrict__ members) {
  const int tid  = threadIdx.x;
  const int lane = tid & 63;
  const int wave = tid >> 6;          // 8 waves

  if (blockIdx.x < NUM_CLASSES) {
    // ---- member scan, ascending order, 1 pass ----
    const int cls = blockIdx.x;
    __shared__ int wave_tot[8];
    const int base_i = tid * 16;                      // 512 thr * 16 = 8192
    const int4* mp = (const int4*)(mask + base_i);
    int flags = 0;                                    // match bitmask (16 bits)
#pragma unroll
    for (int k = 0; k < 4; ++k) {
      const int4 mv = mp[k];
      flags |= (mv.x == cls) << (k * 4 + 0);
      flags |= (mv.y == cls) << (k * 4 + 1);
      flags |= (mv.z == cls) << (k * 4 + 2);
      flags |= (mv.w == cls) << (k * 4 + 3);
    }
    const int cnt = __popc(flags);
    // inclusive scan of cnt within the wave
    int scan = cnt;
#pragma unroll
    for (int off = 1; off < 64; off <<= 1) {
      const int n = __shfl_up(scan, off, 64);
      if (lane >= off) scan += n;
    }
    if (lane == 63) wave_tot[wave] = scan;            // wave total
    __syncthreads();
    int wbase = 0;
    for (int w = 0; w < wave; ++w) wbase += wave_tot[w];
    int pos = wbase + scan - cnt;                     // exclusive prefix
    int* out = members + cls * PER_CLASS;
    int f = flags;
    while (f) {
      const int k = __ffs(f) - 1;
      f &= f - 1;
      out[pos++] = base_i + k;                        // ascending
    }
  } else {
    // ---- scores: one wave per row ----
    const int row = (blockIdx.x - NUM_CLASSES) * 8 + wave;
    const float4* xp = (const float4*)(X + (size_t)row * IN_DIM);
    const float4* wp = (const float4*)W;
    float acc = 0.f;
#pragma unroll
    for (int k = 0; k < 2; ++k) {
      const int i = lane + k * 64;   // 128 float4s per row
      const float4 xv = xp[i];
      const float4 wv = wp[i];
      acc += xv.x * wv.x + xv.y * wv.y + xv.z * wv.z + xv.w * wv.w;
    }
#pragma unroll
    for (int off = 32; off > 0; off >>= 1)
      acc += __shfl_xor(acc, off, 64);
    if (lane == 0) {
      const float z = (acc + b[0]) * 0.01f;
      scores[row] = 1.0f / (1.0f + expf(-z));
    }
  }
}

// ---------------------------------------------------------------------------
// Kernel 2: selection, 64 blocks (4 per class) x 512 threads.
//   Each block: load the class's 512 member scores, mean (double accumulate,
//   bit-identical reduction order to the proven kernel), keys = mean - score.
//   Rank: member j handled by 4 threads, each counting one 128-wide quarter
//   of the key space (float4 LDS broadcast reads), combined via shfl_xor.
//   Exact lax.top_k order: key desc, ties by position asc.
// ---------------------------------------------------------------------------
__global__ __launch_bounds__(512) void select_kernel(
    const int* __restrict__ members, const float* __restrict__ scores,
    int* __restrict__ sel_idx, float* __restrict__ sel_val) {
  const int cls  = blockIdx.x >> 2;
  const int q    = blockIdx.x & 3;     // which 128-member slice we rank
  const int tid  = threadIdx.x;
  const int lane = tid & 63;
  const int wave = tid >> 6;           // 8 waves

  __shared__ float  ssc[PER_CLASS];
  __shared__ float  keys[PER_CLASS];
  __shared__ double wsum[8];
  __shared__ float  meanf;

  const int   mem_t = members[cls * PER_CLASS + tid];
  const float sc_t  = scores[mem_t];
  ssc[tid] = sc_t;

  // mean: same reduction order as the verified kernel (wave shfl + 8 serial)
  double v = (double)sc_t;
#pragma unroll
  for (int off = 32; off > 0; off >>= 1)
    v += __shfl_xor(v, off, 64);
  if (lane == 0) wsum[wave] = v;
  __syncthreads();
  if (tid == 0) {
    double s = 0.0;
    for (int w = 0; w < 8; ++w) s += wsum[w];
    meanf = (float)(s / (double)PER_CLASS);
  }
  __syncthreads();
  const float m = meanf;
  keys[tid] = m - ssc[tid];
  __syncthreads();

  const int   j     = q * 128 + (tid >> 2);  // member this thread helps rank
  const int   seg   = tid & 3;               // quarter of u-space
  const float mykey = keys[j];
  int rank = 0;
  const float4* k4  = (const float4*)(keys + seg * 128);
  const int ubase   = seg * 128;
#pragma unroll 4
  for (int u4 = 0; u4 < 32; ++u4) {
    const float4 kv = k4[u4];
    const int u = ubase + u4 * 4;
    rank += (kv.x > mykey) || (kv.x == mykey && (u + 0) < j);
    rank += (kv.y > mykey) || (kv.y == mykey && (u + 1) < j);
    rank += (kv.z > mykey) || (kv.z == mykey && (u + 2) < j);
    rank += (kv.w > mykey) || (kv.w == mykey && (u + 3) < j);
  }
  // combine the 4 quarter-partials (threads 4a..4a+3, never cross a wave)
  rank += __shfl_xor(rank, 1, 64);
  rank += __shfl_xor(rank, 2, 64);
  if (seg == 0 && rank < KK) {
    sel_val[cls * KK + rank] = ssc[j];
    sel_idx[cls * KK + rank] = members[cls * PER_CLASS + j];
  }
}

// ---------------------------------------------------------------------------
// Kernel 3 (fused): one block (512 threads = 8 waves) per output row r.
//   M_out[r][c] = M[idx[r]][idx[c]]  (stage 32 KB row in LDS, gather, store)
//   X_out[r]    = X[idx[r]] * val[r] (issued before the barrier -> overlaps)
//   mask_out[r] = r >> 8  (by construction — no memory read needed)
// Column-index int4 loads hoisted above the barrier so L2 latency hides
// under the 32 KB row stage. 512 thr + 32 KB LDS -> 4 blocks/CU.
// ---------------------------------------------------------------------------
__global__ __launch_bounds__(512) void gather_kernel(
    const float* __restrict__ M, const float* __restrict__ X,
    const int* __restrict__ sel_idx, const float* __restrict__ sel_val,
    float* __restrict__ m_out, float* __restrict__ x_out,
    float* __restrict__ mask_out) {
  __shared__ float row[NN];    // 32 KB
  const int r   = blockIdx.x;
  const int src = sel_idx[r];

  // Column indices for both gather iterations — issue before the stage wait
  const int4* idx4 = (const int4*)sel_idx;
  const int4 id0 = idx4[threadIdx.x];
  const int4 id1 = idx4[512 + threadIdx.x];

  // Stage M row (32 KB, coalesced, read-once -> nontemporal)
  const vfloat4* mp = (const vfloat4*)(M + (size_t)src * NN);
  vfloat4* rp = (vfloat4*)row;
#pragma unroll
  for (int k = 0; k < 4; ++k) {                // 2048 float4s / 512 thr
    const int i = k * 512 + threadIdx.x;
    rp[i] = __builtin_nontemporal_load(&mp[i]);
  }

  // X row gather+scale (2 KB) — overlaps the M stage, before the barrier
  if (threadIdx.x < 128) {
    const float v = sel_val[r];
    const vfloat4 x =
        ((const vfloat4*)(X + (size_t)src * IN_DIM))[threadIdx.x];
    const vfloat4 o = x * v;
    __builtin_nontemporal_store(
        o, (vfloat4*)(x_out + (size_t)r * IN_DIM) + threadIdx.x);
  }
  if (threadIdx.x == 0) mask_out[r] = (float)(r >> 8);

  __syncthreads();

  // Gather 4096 columns from LDS, store coalesced float4 (write-once)
  vfloat4* out = (vfloat4*)(m_out + (size_t)r * NSEL);
  {
    vfloat4 o;
    o.x = row[id0.x]; o.y = row[id0.y]; o.z = row[id0.z]; o.w = row[id0.w];
    __builtin_nontemporal_store(o, &out[threadIdx.x]);
  }
  {
    vfloat4 o;
    o.x = row[id1.x]; o.y = row[id1.y]; o.z = row[id1.z]; o.w = row[id1.w];
    __builtin_nontemporal_store(o, &out[512 + threadIdx.x]);
  }
}

// ---------------------------------------------------------------------------
extern "C" void kernel_launch(void* const* d_in, const int* in_sizes, int n_in,
                              void* d_out, int out_size, void* d_ws, size_t ws_size,
                              hipStream_t stream) {
  const float* M    = (const float*)d_in[0];   // [1,8192,8192]
  const float* X    = (const float*)d_in[1];   // [1,8192,512]
  const int*   mask = (const int*)  d_in[2];   // [1,8192]
  const float* W    = (const float*)d_in[3];   // [1,512]
  const float* b    = (const float*)d_in[4];   // [1]

  float* out = (float*)d_out;
  // Output layout (flat, return order): M_out | X_out | mask_out
  float* m_out    = out;                                   // 4096*4096
  float* x_out    = out + (size_t)NSEL * NSEL;             // 4096*512
  float* mask_out = x_out + (size_t)NSEL * IN_DIM;         // 4096

  // Workspace layout
  float* scores  = (float*)d_ws;                                    // 8192 f
  int*   sel_idx = (int*)((char*)d_ws + NN * sizeof(float));        // 4096 i
  float* sel_val = (float*)((char*)d_ws + NN * sizeof(float)
                                        + NSEL * sizeof(int));      // 4096 f
  int*   members = (int*)((char*)d_ws + NN * sizeof(float)
                                      + NSEL * sizeof(int)
                                      + NSEL * sizeof(float));      // 16*512 i

  // 1) fused member-scan (16 blocks) + scores (1024 blocks, 8 rows each)
  prep_kernel<<<NUM_CLASSES + NN / 8, 512, 0, stream>>>(X, W, b, mask,
                                                        scores, members);

  // 2) per-class top-k selection (4 blocks per class)
  select_kernel<<<NUM_CLASSES * 4, 512, 0, stream>>>(members, scores,
                                                     sel_idx, sel_val);

  // 3) fused M/X/mask gather
  gather_kernel<<<NSEL, 512, 0, stream>>>(M, X, sel_idx, sel_val,
                                          m_out, x_out, mask_out);
}